// Round 6
// baseline (155.944 us; speedup 1.0000x reference)
//
#include <hip/hip_runtime.h>
#include <stdint.h>

#define HW       262144u     // 512*512
#define NPIX     1048576u    // 4*HW (pixel index fits in 20 bits)
#define NSEL     2048u       // POS_NUM*B = NEG_NUM*B
#define NSEG     1024u       // one segment per front-block per list
#define SEGCAP   16u         // slots/segment (keep-prob 1/32 -> mean ~2.65; P(seg overflow)~1e-9)
#define DENSECAP 3584u       // LDS gather capacity (mean ~2715, +16 sigma)

// workspace byte offsets (~435 KB total)
#define OFF_SEG     0u        // u64[2][NSEG][SEGCAP] = 256 KB (zero-filled unused slots)
#define OFF_VA      262144u   // f32[4096*5]
#define OFF_WA      344064u   // f32[4096*5]
#define OFF_PSUM    425984u   // f32[1024]
#define OFF_PNNZ    430080u   // u32[1024]
#define OFF_DONE    434176u   // u32[33]: done[0..31]=row counters, done[32]=global

// ---------------- Threefry-2x32-20 (JAX partitionable PRNG) ----------------
#define TF_ROUND(r) { x0 += x1; x1 = (x1 << (r)) | (x1 >> (32 - (r))); x1 ^= x0; }
__host__ __device__ inline void threefry2x32_(uint32_t k0, uint32_t k1,
                                              uint32_t& x0, uint32_t& x1) {
  uint32_t k2 = k0 ^ k1 ^ 0x1BD11BDAu;
  x0 += k0; x1 += k1;
  TF_ROUND(13) TF_ROUND(15) TF_ROUND(26) TF_ROUND(6)
  x0 += k1; x1 += k2 + 1u;
  TF_ROUND(17) TF_ROUND(29) TF_ROUND(16) TF_ROUND(24)
  x0 += k2; x1 += k0 + 2u;
  TF_ROUND(13) TF_ROUND(15) TF_ROUND(26) TF_ROUND(6)
  x0 += k0; x1 += k1 + 3u;
  TF_ROUND(17) TF_ROUND(29) TF_ROUND(16) TF_ROUND(24)
  x0 += k1; x1 += k2 + 4u;
  TF_ROUND(13) TF_ROUND(15) TF_ROUND(26) TF_ROUND(6)
  x0 += k2; x1 += k0 + 5u;
}

// ---------------- front: mask + PRNG + fixed-threshold compaction ----------------
// keep iff top-5 bits of the 23-bit random == 0x1F (keep-prob 1/32). Keep-set is
// upward-closed in key order; E[survivors] ~2715 >= 2048 at ~13 sigma, so the
// exact top-2048 is a subset of the survivors. Unused slots are zeroed (bit43
// marker distinguishes real keys), so the back-end sweeps the array blindly.
// Also zeroes the done-counters used by k_pair's fused final reduction.
__global__ __launch_bounds__(256) void k_front(
    const float* __restrict__ pfegc, const float* __restrict__ ppre,
    const float* __restrict__ gt,
    uint32_t kp0, uint32_t kp1, uint32_t kn0, uint32_t kn1,
    uint64_t* __restrict__ seg, uint32_t* __restrict__ done) {
  __shared__ uint32_t cnt2[2];
  int t = threadIdx.x;
  uint32_t b = blockIdx.x;
  if (t < 2) cnt2[t] = 0;
  if (b == 0 && t < 33) done[t] = 0u;       // re-init (ws poisoned 0xAA each launch)
  if (t < 2 * (int)SEGCAP) {                // zero-fill this block's two segments
    uint32_t list = (uint32_t)t / SEGCAP, slot = (uint32_t)t % SEGCAP;
    seg[((size_t)list * NSEG + b) * SEGCAP + slot] = 0ull;
  }
  __syncthreads();
  uint32_t base = b * 1024u + (uint32_t)t * 4u;
  float4 pf = *(const float4*)(pfegc + base);
  float pfa[4] = { pf.x, pf.y, pf.z, pf.w };
  bool any = (pf.x >= 0.5f) || (pf.y >= 0.5f) || (pf.z >= 0.5f) || (pf.w >= 0.5f);
  if (any) {
    uint32_t hw = base & (HW - 1u);
    uint32_t bb = base >> 18;                 // base..base+3 share the image
    const float* pp = ppre + (size_t)bb * 3u * HW + hw;
    float4 p0 = *(const float4*)pp;
    float4 p1 = *(const float4*)(pp + HW);
    float4 p2 = *(const float4*)(pp + 2u * HW);
    float4 g4 = *(const float4*)(gt + base);
    float p0a[4] = { p0.x, p0.y, p0.z, p0.w };
    float p1a[4] = { p1.x, p1.y, p1.z, p1.w };
    float p2a[4] = { p2.x, p2.y, p2.z, p2.w };
    float ga[4]  = { g4.x, g4.y, g4.z, g4.w };
    #pragma unroll
    for (int j = 0; j < 4; ++j) {
      if (pfa[j] >= 0.5f && p0a[j] >= p1a[j] && p0a[j] >= p2a[j]) {
        uint32_t i = base + (uint32_t)j;
        bool gfg = ga[j] > 0.5f;
        uint32_t x0 = 0u, x1 = i;
        threefry2x32_(gfg ? kp0 : kn0, gfg ? kp1 : kn1, x0, x1);
        uint32_t r23 = (x0 ^ x1) >> 9;
        if ((r23 >> 18) == 0x1Fu) {           // fixed prefilter, keep-prob 1/32
          uint32_t list = gfg ? 0u : 1u;
          uint32_t r = atomicAdd(&cnt2[list], 1u);     // u32 LDS atomic, rare
          if (r < SEGCAP)
            seg[((size_t)list * NSEG + b) * SEGCAP + r] =
                (1ull << 43) | ((uint64_t)r23 << 20) | (uint64_t)(0xFFFFFu ^ i);
        }
      }
    }
  }
}

// ---------------- select exact top-2048 + project (fused; 1 block/list) ----------------
// Coalesced sweep of the 128 KB segment half; ballot-aggregated LDS push
// (1 atomic per wave); 4-round 11-bit radix select; survivor indices collected
// into LDS (hist region, freed after select); gather + rank-5 projection inline.
__global__ __launch_bounds__(256) void k_selproj(
    const uint64_t* __restrict__ seg,
    const float* __restrict__ Wm, const float* __restrict__ bfc,
    const float* __restrict__ d1,
    float* __restrict__ va, float* __restrict__ wa) {
  __shared__ uint64_t dense[DENSECAP];   // 28 KB
  __shared__ uint32_t hist[2048];        // 8 KB; reused as idx[2048] after select
  __shared__ uint32_t part[256];
  __shared__ uint32_t cnt, rank, skk;
  __shared__ int gsel;
  __shared__ uint64_t spref;
  __shared__ float sG[25];
  __shared__ float sGw[4][25];
  int t = threadIdx.x;
  int list = blockIdx.x;
  uint32_t lane = (uint32_t)t & 63u;
  // ---- G = [W|b]^T [W|b] via shuffle reduction (no atomics) ----
  {
    float4 wr = *(const float4*)(Wm + t * 4);
    float av[5] = { wr.x, wr.y, wr.z, wr.w, bfc[t] };
    int wvi = t >> 6;
    #pragma unroll
    for (int p = 0; p < 5; ++p)
      #pragma unroll
      for (int q = p; q < 5; ++q) {
        float g = av[p] * av[q];
        #pragma unroll
        for (int off = 32; off > 0; off >>= 1)
          g += __shfl_xor(g, off, 64);
        if (lane == 0) sGw[wvi][p * 5 + q] = g;
      }
  }
  if (t == 0) { cnt = 0; rank = 0; spref = 0ull; skk = NSEL; }
  __syncthreads();
  if (t < 25) {
    int p = t / 5, q = t % 5;
    int pp = p < q ? p : q, qq = p < q ? q : p;
    sG[t] = sGw[0][pp * 5 + qq] + sGw[1][pp * 5 + qq]
          + sGw[2][pp * 5 + qq] + sGw[3][pp * 5 + qq];
  }
  __syncthreads();
  const uint64_t* sp = seg + (size_t)list * NSEG * SEGCAP;
  // ---- coalesced sweep: 16384 u64 in 32 iterations of u64x2 per thread ----
  for (int it = 0; it < 32; ++it) {
    uint32_t g = (uint32_t)it * 512u + (uint32_t)t * 2u;
    uint64_t k0 = sp[g];
    uint64_t k1 = sp[g + 1u];
    #pragma unroll
    for (int h = 0; h < 2; ++h) {
      uint64_t key = h ? k1 : k0;
      bool v = (key >> 43) != 0ull;
      unsigned long long m = __ballot(v);
      uint32_t bs = 0;
      if (lane == 0) bs = atomicAdd(&cnt, (uint32_t)__popcll(m));
      bs = (uint32_t)__shfl((int)bs, 0, 64);
      if (v) {
        uint32_t s = bs + (uint32_t)__popcll(m & ((1ull << lane) - 1ull));
        if (s < DENSECAP) dense[s] = key;
      }
    }
  }
  __syncthreads();
  uint32_t n = cnt; if (n > DENSECAP) n = DENSECAP;
  // ---- 4-round 11-bit radix select of the exact 2048th-largest key ----
  for (int r = 0; r < 4; ++r) {
    #pragma unroll
    for (int e = 0; e < 8; ++e) hist[t * 8 + e] = 0;
    __syncthreads();
    int csp = 44 - 11 * r;
    int cs = csp - 11;
    uint64_t pref = spref;
    for (uint32_t j = t; j < n; j += 256) {
      uint64_t key = dense[j];
      if ((key >> csp) == pref)
        atomicAdd(&hist[(uint32_t)(key >> cs) & 0x7FFu], 1u);
    }
    __syncthreads();
    uint32_t ss = 0;
    #pragma unroll
    for (int e = 0; e < 8; ++e) ss += hist[t * 8 + e];
    part[t] = ss;
    __syncthreads();
    for (int off = 1; off < 256; off <<= 1) {
      uint32_t x = part[t];
      uint32_t y = (t + off < 256) ? part[t + off] : 0u;
      __syncthreads();
      part[t] = x + y;
      __syncthreads();
    }
    uint32_t k = skk;
    if (part[t] >= k && (t == 255 || part[t + 1] < k)) gsel = t;
    __syncthreads();
    if (t == 0) {
      int g = gsel;
      uint32_t cum = (g < 255) ? part[g + 1] : 0u;
      int d = g * 8;
      for (int e = g * 8 + 7; e >= g * 8; --e) {
        uint32_t he = hist[e];
        if (cum + he >= k) { d = e; break; }
        cum += he;
      }
      skk = k - cum;
      spref = (pref << 11) | (uint64_t)(uint32_t)d;
    }
    __syncthreads();
  }
  // ---- collect survivor pixel-indices into LDS (hist region; exactly 2048,
  //      keys are unique so no tie overflow) ----
  uint64_t thr = spref;
  uint32_t niter = (n + 255u) >> 8;
  for (uint32_t it2 = 0; it2 < niter; ++it2) {
    uint32_t j = it2 * 256u + (uint32_t)t;
    uint64_t key = 0ull;
    bool v = false;
    if (j < n) { key = dense[j]; v = key >= thr; }
    unsigned long long m = __ballot(v);
    uint32_t bs = 0;
    if (lane == 0) bs = atomicAdd(&rank, (uint32_t)__popcll(m));
    bs = (uint32_t)__shfl((int)bs, 0, 64);
    if (v) {
      uint32_t s = bs + (uint32_t)__popcll(m & ((1ull << lane) - 1ull));
      if (s < NSEL) hist[s] = 0xFFFFFu ^ (uint32_t)(key & 0xFFFFFu);
    }
  }
  __syncthreads();
  // ---- project: v = y/|proj|, w = G v (8 points/thread, parallel gathers) ----
  for (uint32_t j = t; j < NSEL; j += 256) {
    uint32_t idx = hist[j] & (NPIX - 1u);
    uint32_t hw = idx & (HW - 1u);
    uint32_t bb = idx >> 18;
    const float* f = d1 + ((size_t)bb << 20) + hw;
    float y[5] = { f[0], f[HW], f[2u * HW], f[3u * HW], 1.0f };
    float z[5]; float n2 = 0.f;
    #pragma unroll
    for (int p = 0; p < 5; ++p) {
      float acc = 0.f;
      #pragma unroll
      for (int q = 0; q < 5; ++q) acc += sG[p * 5 + q] * y[q];
      z[p] = acc; n2 += acc * y[p];                     // = |proj|^2
    }
    n2 = fmaxf(n2, 0.f);
    float inv = 1.0f / fmaxf(sqrtf(n2), 1e-8f);
    uint32_t s5 = ((uint32_t)list * NSEL + j) * 5u;
    #pragma unroll
    for (int p = 0; p < 5; ++p) {
      va[s5 + p] = y[p] * inv;
      wa[s5 + p] = z[p] * inv;
    }
  }
}

// ---------------- pairwise loss + fused final reduction (last-block pattern) ----------------
__global__ __launch_bounds__(256) void k_pair(
    const float* __restrict__ va, const float* __restrict__ wa,
    float* __restrict__ psum, uint32_t* __restrict__ pnnz,
    uint32_t* __restrict__ done, float* __restrict__ out) {
  __shared__ float sv[128 * 5], sw[128 * 5];
  __shared__ float rs[256];
  __shared__ uint32_t rn[256];
  __shared__ int islast;
  int i0 = blockIdx.x * 128, j0 = blockIdx.y * 128;
  int t = threadIdx.x;
  for (int u = t; u < 640; u += 256) { sv[u] = va[i0 * 5 + u]; sw[u] = wa[j0 * 5 + u]; }
  __syncthreads();
  int ty = t >> 4, tx = t & 15;
  float rv[8][5], rw[8][5];
  #pragma unroll
  for (int a = 0; a < 8; ++a)
    #pragma unroll
    for (int p = 0; p < 5; ++p) {
      rv[a][p] = sv[(ty * 8 + a) * 5 + p];
      rw[a][p] = sw[(tx * 8 + a) * 5 + p];
    }
  float lsum = 0.f; uint32_t lnz = 0;
  #pragma unroll
  for (int a = 0; a < 8; ++a) {
    int gi = i0 + ty * 8 + a;
    #pragma unroll
    for (int q = 0; q < 8; ++q) {
      int gj = j0 + tx * 8 + q;
      float c = rv[a][0]*rw[q][0] + rv[a][1]*rw[q][1] + rv[a][2]*rw[q][2]
              + rv[a][3]*rw[q][3] + rv[a][4]*rw[q][4];
      float s = c * 10.0f;                     // / TAU
      if (gi != gj) {
        if (((gi ^ gj) & 2048) == 0) {         // same block (pos-pos / neg-neg)
          float m = fmaxf(0.5f - s, 0.f);
          lsum += m * m;
          lnz += (m > 0.f) ? 1u : 0u;
        } else {                               // cross block
          lsum += s * s;
          lnz += (s != 0.f) ? 1u : 0u;
        }
      }
    }
  }
  rs[t] = lsum; rn[t] = lnz;
  __syncthreads();
  for (int off = 128; off > 0; off >>= 1) {
    if (t < off) { rs[t] += rs[t + off]; rn[t] += rn[t + off]; }
    __syncthreads();
  }
  int bid = blockIdx.y * gridDim.x + blockIdx.x;
  if (t == 0) {
    atomicExch(&psum[bid], rs[0]);             // device-scope write of partials
    atomicExch(&pnnz[bid], rn[0]);
    __threadfence();
    int last = 0;
    uint32_t o1 = atomicAdd(&done[blockIdx.y], 1u);   // <=32-way contention
    if (o1 == 31u) {
      uint32_t o2 = atomicAdd(&done[32], 1u);         // <=32-way contention
      last = (o2 == 31u);
    }
    islast = last;
  }
  __syncthreads();
  if (islast) {                                // exactly one block reduces
    float s = 0.f; uint32_t nz = 0;
    for (int j = t; j < 1024; j += 256) {
      s += atomicAdd(&psum[j], 0.0f);          // atomic loads: device-scope coherent
      nz += atomicAdd(&pnnz[j], 0u);
    }
    __syncthreads();
    rs[t] = s; rn[t] = nz;
    __syncthreads();
    for (int off = 128; off > 0; off >>= 1) {
      if (t < off) { rs[t] += rs[t + off]; rn[t] += rn[t + off]; }
      __syncthreads();
    }
    if (t == 0) out[0] = rs[0] / (float)rn[0];
  }
}

extern "C" void kernel_launch(void* const* d_in, const int* in_sizes, int n_in,
                              void* d_out, int out_size, void* d_ws, size_t ws_size,
                              hipStream_t stream) {
  (void)in_sizes; (void)n_in; (void)out_size; (void)ws_size;
  const float* d1    = (const float*)d_in[0];
  const float* pfegc = (const float*)d_in[1];
  const float* ppre  = (const float*)d_in[2];
  const float* gt    = (const float*)d_in[3];
  const float* W     = (const float*)d_in[4];
  const float* bfc   = (const float*)d_in[5];
  float* out = (float*)d_out;

  uint8_t* base = (uint8_t*)d_ws;
  uint64_t* seg  = (uint64_t*)(base + OFF_SEG);
  float*    va   = (float*)(base + OFF_VA);
  float*    wa   = (float*)(base + OFF_WA);
  float*    psum = (float*)(base + OFF_PSUM);
  uint32_t* pnnz = (uint32_t*)(base + OFF_PNNZ);
  uint32_t* done = (uint32_t*)(base + OFF_DONE);

  // jax.random.key(42), partitionable split: kp = tf(0,42,{0,0}), kn = tf(0,42,{0,1})
  uint32_t kp0 = 0u, kp1 = 0u; threefry2x32_(0u, 42u, kp0, kp1);
  uint32_t kn0 = 0u, kn1 = 1u; threefry2x32_(0u, 42u, kn0, kn1);

  k_front<<<NSEG, 256, 0, stream>>>(pfegc, ppre, gt, kp0, kp1, kn0, kn1, seg, done);
  k_selproj<<<2, 256, 0, stream>>>(seg, W, bfc, d1, va, wa);
  k_pair<<<dim3(32, 32), 256, 0, stream>>>(va, wa, psum, pnnz, done, out);
}

// Round 7
// 137.983 us; speedup vs baseline: 1.1302x; 1.1302x over previous
//
#include <hip/hip_runtime.h>
#include <stdint.h>

#define HW       262144u     // 512*512
#define NPIX     1048576u    // 4*HW (pixel index fits in 20 bits)
#define NSEL     2048u       // POS_NUM*B = NEG_NUM*B
#define NSEG     1024u       // one segment per front-block per list
#define SEGCAP   16u         // slots/segment (keep-prob 1/32 -> mean ~2.65; P(seg overflow)~1e-9)
#define DENSECAP 3584u       // LDS gather capacity (mean ~2715, +16 sigma)

// workspace byte offsets (~455 KB total)
#define OFF_SEG     0u        // u64[2][NSEG][SEGCAP] = 256 KB (zero-filled unused slots)
#define OFF_IDX     262144u   // u32[4096] pos then neg
#define OFF_VA      278528u   // f32[4096*5]
#define OFF_WA      360448u   // f32[4096*5]
#define OFF_PSUM    442368u   // f32[1024]
#define OFF_PNNZ    446464u   // u32[1024]
#define OFF_DONE    450560u   // u32[33]: done[0..31]=row counters, done[32]=global

// ---------------- Threefry-2x32-20 (JAX partitionable PRNG) ----------------
#define TF_ROUND(r) { x0 += x1; x1 = (x1 << (r)) | (x1 >> (32 - (r))); x1 ^= x0; }
__host__ __device__ inline void threefry2x32_(uint32_t k0, uint32_t k1,
                                              uint32_t& x0, uint32_t& x1) {
  uint32_t k2 = k0 ^ k1 ^ 0x1BD11BDAu;
  x0 += k0; x1 += k1;
  TF_ROUND(13) TF_ROUND(15) TF_ROUND(26) TF_ROUND(6)
  x0 += k1; x1 += k2 + 1u;
  TF_ROUND(17) TF_ROUND(29) TF_ROUND(16) TF_ROUND(24)
  x0 += k2; x1 += k0 + 2u;
  TF_ROUND(13) TF_ROUND(15) TF_ROUND(26) TF_ROUND(6)
  x0 += k0; x1 += k1 + 3u;
  TF_ROUND(17) TF_ROUND(29) TF_ROUND(16) TF_ROUND(24)
  x0 += k1; x1 += k2 + 4u;
  TF_ROUND(13) TF_ROUND(15) TF_ROUND(26) TF_ROUND(6)
  x0 += k2; x1 += k0 + 5u;
}

// ---------------- front: mask + PRNG + fixed-threshold compaction ----------------
// keep iff top-5 bits of the 23-bit random == 0x1F (keep-prob 1/32). Keep-set is
// upward-closed in key order; E[survivors] ~2715 >= 2048 at ~13 sigma, so the
// exact top-2048 is a subset of the survivors. Unused slots are zeroed (bit43
// marker distinguishes real keys), so the back-end sweeps the array blindly.
// Also zeroes the done-counters used by k_pair's fused final reduction.
__global__ __launch_bounds__(256) void k_front(
    const float* __restrict__ pfegc, const float* __restrict__ ppre,
    const float* __restrict__ gt,
    uint32_t kp0, uint32_t kp1, uint32_t kn0, uint32_t kn1,
    uint64_t* __restrict__ seg, uint32_t* __restrict__ done) {
  __shared__ uint32_t cnt2[2];
  int t = threadIdx.x;
  uint32_t b = blockIdx.x;
  if (t < 2) cnt2[t] = 0;
  if (b == 0 && t < 33) done[t] = 0u;       // re-init (ws poisoned 0xAA each launch)
  if (t < 2 * (int)SEGCAP) {                // zero-fill this block's two segments
    uint32_t list = (uint32_t)t / SEGCAP, slot = (uint32_t)t % SEGCAP;
    seg[((size_t)list * NSEG + b) * SEGCAP + slot] = 0ull;
  }
  __syncthreads();
  uint32_t base = b * 1024u + (uint32_t)t * 4u;
  float4 pf = *(const float4*)(pfegc + base);
  float pfa[4] = { pf.x, pf.y, pf.z, pf.w };
  bool any = (pf.x >= 0.5f) || (pf.y >= 0.5f) || (pf.z >= 0.5f) || (pf.w >= 0.5f);
  if (any) {
    uint32_t hw = base & (HW - 1u);
    uint32_t bb = base >> 18;                 // base..base+3 share the image
    const float* pp = ppre + (size_t)bb * 3u * HW + hw;
    float4 p0 = *(const float4*)pp;
    float4 p1 = *(const float4*)(pp + HW);
    float4 p2 = *(const float4*)(pp + 2u * HW);
    float4 g4 = *(const float4*)(gt + base);
    float p0a[4] = { p0.x, p0.y, p0.z, p0.w };
    float p1a[4] = { p1.x, p1.y, p1.z, p1.w };
    float p2a[4] = { p2.x, p2.y, p2.z, p2.w };
    float ga[4]  = { g4.x, g4.y, g4.z, g4.w };
    #pragma unroll
    for (int j = 0; j < 4; ++j) {
      if (pfa[j] >= 0.5f && p0a[j] >= p1a[j] && p0a[j] >= p2a[j]) {
        uint32_t i = base + (uint32_t)j;
        bool gfg = ga[j] > 0.5f;
        uint32_t x0 = 0u, x1 = i;
        threefry2x32_(gfg ? kp0 : kn0, gfg ? kp1 : kn1, x0, x1);
        uint32_t r23 = (x0 ^ x1) >> 9;
        if ((r23 >> 18) == 0x1Fu) {           // fixed prefilter, keep-prob 1/32
          uint32_t list = gfg ? 0u : 1u;
          uint32_t r = atomicAdd(&cnt2[list], 1u);     // u32 LDS atomic, rare
          if (r < SEGCAP)
            seg[((size_t)list * NSEG + b) * SEGCAP + r] =
                (1ull << 43) | ((uint64_t)r23 << 20) | (uint64_t)(0xFFFFFu ^ i);
        }
      }
    }
  }
}

// ---------------- select exact top-2048 (1 block/list) ----------------
// count -> scan -> scatter sweep (no per-iteration ballot/atomic serialization):
// Phase A: 64 fully-pipelined independent loads/thread, count valid.
// One 256-wide scan. Phase B: re-load (L2-hot) and scatter to dense at
// per-thread bases. Then 4-round 11-bit radix select; survivors -> idxbuf.
__global__ __launch_bounds__(256) void k_sel(
    const uint64_t* __restrict__ seg, uint32_t* __restrict__ idxbuf) {
  __shared__ uint64_t dense[DENSECAP];   // 28 KB
  __shared__ uint32_t hist[2048];        // 8 KB
  __shared__ uint32_t part[256];
  __shared__ uint32_t skk, rank, ntot;
  __shared__ int gsel;
  __shared__ uint64_t spref;
  int t = threadIdx.x;
  int list = blockIdx.x;
  uint32_t lane = (uint32_t)t & 63u;
  if (t == 0) { spref = 0ull; skk = NSEL; rank = 0; }
  const uint64_t* sp = seg + (size_t)list * NSEG * SEGCAP;
  // ---- Phase A: count valid keys (bit43 marker); all loads independent ----
  uint32_t c = 0;
  #pragma unroll
  for (int it = 0; it < 32; ++it) {
    uint32_t g = (uint32_t)it * 512u + (uint32_t)t * 2u;
    uint64_t k0 = sp[g];
    uint64_t k1 = sp[g + 1u];
    c += (uint32_t)(k0 >> 43) + (uint32_t)(k1 >> 43);
  }
  part[t] = c;
  __syncthreads();
  for (int off = 1; off < 256; off <<= 1) {
    uint32_t x = part[t];
    uint32_t add = (t >= off) ? part[t - off] : 0u;
    __syncthreads();
    part[t] = x + add;
    __syncthreads();
  }
  uint32_t wbase = part[t] - c;          // exclusive prefix = this thread's base
  if (t == 255) ntot = part[255];
  // ---- Phase B: re-load (L2-hot) and scatter to dense ----
  #pragma unroll
  for (int it = 0; it < 32; ++it) {
    uint32_t g = (uint32_t)it * 512u + (uint32_t)t * 2u;
    uint64_t k0 = sp[g];
    uint64_t k1 = sp[g + 1u];
    if (k0 >> 43) { if (wbase < DENSECAP) dense[wbase] = k0; ++wbase; }
    if (k1 >> 43) { if (wbase < DENSECAP) dense[wbase] = k1; ++wbase; }
  }
  __syncthreads();
  uint32_t n = ntot; if (n > DENSECAP) n = DENSECAP;
  // ---- 4-round 11-bit radix select of the exact 2048th-largest key ----
  for (int r = 0; r < 4; ++r) {
    #pragma unroll
    for (int e = 0; e < 8; ++e) hist[t * 8 + e] = 0;
    __syncthreads();
    int csp = 44 - 11 * r;
    int cs = csp - 11;
    uint64_t pref = spref;
    for (uint32_t j = t; j < n; j += 256) {
      uint64_t key = dense[j];
      if ((key >> csp) == pref)
        atomicAdd(&hist[(uint32_t)(key >> cs) & 0x7FFu], 1u);
    }
    __syncthreads();
    uint32_t ss = 0;
    #pragma unroll
    for (int e = 0; e < 8; ++e) ss += hist[t * 8 + e];
    part[t] = ss;
    __syncthreads();
    for (int off = 1; off < 256; off <<= 1) {
      uint32_t x = part[t];
      uint32_t y = (t + off < 256) ? part[t + off] : 0u;
      __syncthreads();
      part[t] = x + y;
      __syncthreads();
    }
    uint32_t k = skk;
    if (part[t] >= k && (t == 255 || part[t + 1] < k)) gsel = t;
    __syncthreads();
    if (t == 0) {
      int g = gsel;
      uint32_t cum = (g < 255) ? part[g + 1] : 0u;
      int d = g * 8;
      for (int e = g * 8 + 7; e >= g * 8; --e) {
        uint32_t he = hist[e];
        if (cum + he >= k) { d = e; break; }
        cum += he;
      }
      skk = k - cum;
      spref = (pref << 11) | (uint64_t)(uint32_t)d;
    }
    __syncthreads();
  }
  // ---- collect survivor indices (ballot-aggregated; exactly 2048, unique keys) ----
  uint64_t thr = spref;
  uint32_t niter = (n + 255u) >> 8;
  for (uint32_t it2 = 0; it2 < niter; ++it2) {
    uint32_t j = it2 * 256u + (uint32_t)t;
    uint64_t key = 0ull;
    bool v = false;
    if (j < n) { key = dense[j]; v = key >= thr; }
    unsigned long long m = __ballot(v);
    uint32_t bs = 0;
    if (lane == 0) bs = atomicAdd(&rank, (uint32_t)__popcll(m));
    bs = (uint32_t)__shfl((int)bs, 0, 64);
    if (v) {
      uint32_t s = bs + (uint32_t)__popcll(m & ((1ull << lane) - 1ull));
      if (s < NSEL)
        idxbuf[(uint32_t)list * NSEL + s] = 0xFFFFFu ^ (uint32_t)(key & 0xFFFFFu);
    }
  }
}

// ---------------- project: v = y/|proj|, w = G v (1 point/thread, 16 blocks) ----------------
__global__ __launch_bounds__(256) void k_proj(
    const uint32_t* __restrict__ idxbuf, const float* __restrict__ Wm,
    const float* __restrict__ bfc, const float* __restrict__ d1,
    float* __restrict__ va, float* __restrict__ wa) {
  __shared__ float sG[25];
  __shared__ float sGw[4][25];
  int t = threadIdx.x;
  // ---- G = [W|b]^T [W|b] via shuffle reduction (no atomics) ----
  {
    float4 wr = *(const float4*)(Wm + t * 4);
    float av[5] = { wr.x, wr.y, wr.z, wr.w, bfc[t] };
    int lane = t & 63, wvi = t >> 6;
    #pragma unroll
    for (int p = 0; p < 5; ++p)
      #pragma unroll
      for (int q = p; q < 5; ++q) {
        float g = av[p] * av[q];
        #pragma unroll
        for (int off = 32; off > 0; off >>= 1)
          g += __shfl_xor(g, off, 64);
        if (lane == 0) sGw[wvi][p * 5 + q] = g;
      }
  }
  __syncthreads();
  if (t < 25) {
    int p = t / 5, q = t % 5;
    int pp = p < q ? p : q, qq = p < q ? q : p;
    sG[t] = sGw[0][pp * 5 + qq] + sGw[1][pp * 5 + qq]
          + sGw[2][pp * 5 + qq] + sGw[3][pp * 5 + qq];
  }
  __syncthreads();
  uint32_t tg = blockIdx.x * 256u + (uint32_t)t;      // 0..4095
  uint32_t idx = idxbuf[tg] & (NPIX - 1u);
  uint32_t hw = idx & (HW - 1u);
  uint32_t bb = idx >> 18;
  const float* f = d1 + ((size_t)bb << 20) + hw;
  float y[5] = { f[0], f[HW], f[2u * HW], f[3u * HW], 1.0f };
  float z[5]; float n2 = 0.f;
  #pragma unroll
  for (int p = 0; p < 5; ++p) {
    float acc = 0.f;
    #pragma unroll
    for (int q = 0; q < 5; ++q) acc += sG[p * 5 + q] * y[q];
    z[p] = acc; n2 += acc * y[p];                     // = |proj|^2
  }
  n2 = fmaxf(n2, 0.f);
  float inv = 1.0f / fmaxf(sqrtf(n2), 1e-8f);
  uint32_t s5 = tg * 5u;
  #pragma unroll
  for (int p = 0; p < 5; ++p) {
    va[s5 + p] = y[p] * inv;
    wa[s5 + p] = z[p] * inv;
  }
}

// ---------------- pairwise loss + fused final reduction (last-block pattern) ----------------
__global__ __launch_bounds__(256) void k_pair(
    const float* __restrict__ va, const float* __restrict__ wa,
    float* __restrict__ psum, uint32_t* __restrict__ pnnz,
    uint32_t* __restrict__ done, float* __restrict__ out) {
  __shared__ float sv[128 * 5], sw[128 * 5];
  __shared__ float rs[256];
  __shared__ uint32_t rn[256];
  __shared__ int islast;
  int i0 = blockIdx.x * 128, j0 = blockIdx.y * 128;
  int t = threadIdx.x;
  for (int u = t; u < 640; u += 256) { sv[u] = va[i0 * 5 + u]; sw[u] = wa[j0 * 5 + u]; }
  __syncthreads();
  int ty = t >> 4, tx = t & 15;
  float rv[8][5], rw[8][5];
  #pragma unroll
  for (int a = 0; a < 8; ++a)
    #pragma unroll
    for (int p = 0; p < 5; ++p) {
      rv[a][p] = sv[(ty * 8 + a) * 5 + p];
      rw[a][p] = sw[(tx * 8 + a) * 5 + p];
    }
  float lsum = 0.f; uint32_t lnz = 0;
  #pragma unroll
  for (int a = 0; a < 8; ++a) {
    int gi = i0 + ty * 8 + a;
    #pragma unroll
    for (int q = 0; q < 8; ++q) {
      int gj = j0 + tx * 8 + q;
      float c = rv[a][0]*rw[q][0] + rv[a][1]*rw[q][1] + rv[a][2]*rw[q][2]
              + rv[a][3]*rw[q][3] + rv[a][4]*rw[q][4];
      float s = c * 10.0f;                     // / TAU
      if (gi != gj) {
        if (((gi ^ gj) & 2048) == 0) {         // same block (pos-pos / neg-neg)
          float m = fmaxf(0.5f - s, 0.f);
          lsum += m * m;
          lnz += (m > 0.f) ? 1u : 0u;
        } else {                               // cross block
          lsum += s * s;
          lnz += (s != 0.f) ? 1u : 0u;
        }
      }
    }
  }
  rs[t] = lsum; rn[t] = lnz;
  __syncthreads();
  for (int off = 128; off > 0; off >>= 1) {
    if (t < off) { rs[t] += rs[t + off]; rn[t] += rn[t + off]; }
    __syncthreads();
  }
  int bid = blockIdx.y * gridDim.x + blockIdx.x;
  if (t == 0) {
    atomicExch(&psum[bid], rs[0]);             // device-scope write of partials
    atomicExch(&pnnz[bid], rn[0]);
    __threadfence();
    int last = 0;
    uint32_t o1 = atomicAdd(&done[blockIdx.y], 1u);   // <=32-way contention
    if (o1 == 31u) {
      uint32_t o2 = atomicAdd(&done[32], 1u);         // <=32-way contention
      last = (o2 == 31u);
    }
    islast = last;
  }
  __syncthreads();
  if (islast) {                                // exactly one block reduces
    float s = 0.f; uint32_t nz = 0;
    for (int j = t; j < 1024; j += 256) {
      s += atomicAdd(&psum[j], 0.0f);          // atomic loads: device-scope coherent
      nz += atomicAdd(&pnnz[j], 0u);
    }
    __syncthreads();
    rs[t] = s; rn[t] = nz;
    __syncthreads();
    for (int off = 128; off > 0; off >>= 1) {
      if (t < off) { rs[t] += rs[t + off]; rn[t] += rn[t + off]; }
      __syncthreads();
    }
    if (t == 0) out[0] = rs[0] / (float)rn[0];
  }
}

extern "C" void kernel_launch(void* const* d_in, const int* in_sizes, int n_in,
                              void* d_out, int out_size, void* d_ws, size_t ws_size,
                              hipStream_t stream) {
  (void)in_sizes; (void)n_in; (void)out_size; (void)ws_size;
  const float* d1    = (const float*)d_in[0];
  const float* pfegc = (const float*)d_in[1];
  const float* ppre  = (const float*)d_in[2];
  const float* gt    = (const float*)d_in[3];
  const float* W     = (const float*)d_in[4];
  const float* bfc   = (const float*)d_in[5];
  float* out = (float*)d_out;

  uint8_t* base = (uint8_t*)d_ws;
  uint64_t* seg    = (uint64_t*)(base + OFF_SEG);
  uint32_t* idxbuf = (uint32_t*)(base + OFF_IDX);
  float*    va     = (float*)(base + OFF_VA);
  float*    wa     = (float*)(base + OFF_WA);
  float*    psum   = (float*)(base + OFF_PSUM);
  uint32_t* pnnz   = (uint32_t*)(base + OFF_PNNZ);
  uint32_t* done   = (uint32_t*)(base + OFF_DONE);

  // jax.random.key(42), partitionable split: kp = tf(0,42,{0,0}), kn = tf(0,42,{0,1})
  uint32_t kp0 = 0u, kp1 = 0u; threefry2x32_(0u, 42u, kp0, kp1);
  uint32_t kn0 = 0u, kn1 = 1u; threefry2x32_(0u, 42u, kn0, kn1);

  k_front<<<NSEG, 256, 0, stream>>>(pfegc, ppre, gt, kp0, kp1, kn0, kn1, seg, done);
  k_sel<<<2, 256, 0, stream>>>(seg, idxbuf);
  k_proj<<<16, 256, 0, stream>>>(idxbuf, W, bfc, d1, va, wa);
  k_pair<<<dim3(32, 32), 256, 0, stream>>>(va, wa, psum, pnnz, done, out);
}

// Round 8
// 126.232 us; speedup vs baseline: 1.2354x; 1.0931x over previous
//
#include <hip/hip_runtime.h>
#include <stdint.h>

#define HW       262144u     // 512*512
#define NPIX     1048576u    // 4*HW (pixel index fits in 20 bits)
#define NSEL     2048u       // POS_NUM*B = NEG_NUM*B
#define NSEG     1024u       // one segment per front-block per list
#define SEGCAP   16u         // slots/segment (keep-prob 1/32 -> mean ~2.65; P(seg overflow)~1e-9)
#define DENSECAP 3584u       // LDS gather capacity (mean ~2715, +16 sigma)

// workspace byte offsets (~450 KB total)
#define OFF_SEG     0u        // u64[2][NSEG][SEGCAP] = 256 KB (zero-filled unused slots)
#define OFF_IDX     262144u   // u32[4096] pos then neg
#define OFF_VA      278528u   // f32[4096*5]
#define OFF_WA      360448u   // f32[4096*5]
#define OFF_PSUM    442368u   // f32[1024]
#define OFF_PNNZ    446464u   // u32[1024]

// ---------------- Threefry-2x32-20 (JAX partitionable PRNG) ----------------
#define TF_ROUND(r) { x0 += x1; x1 = (x1 << (r)) | (x1 >> (32 - (r))); x1 ^= x0; }
__host__ __device__ inline void threefry2x32_(uint32_t k0, uint32_t k1,
                                              uint32_t& x0, uint32_t& x1) {
  uint32_t k2 = k0 ^ k1 ^ 0x1BD11BDAu;
  x0 += k0; x1 += k1;
  TF_ROUND(13) TF_ROUND(15) TF_ROUND(26) TF_ROUND(6)
  x0 += k1; x1 += k2 + 1u;
  TF_ROUND(17) TF_ROUND(29) TF_ROUND(16) TF_ROUND(24)
  x0 += k2; x1 += k0 + 2u;
  TF_ROUND(13) TF_ROUND(15) TF_ROUND(26) TF_ROUND(6)
  x0 += k0; x1 += k1 + 3u;
  TF_ROUND(17) TF_ROUND(29) TF_ROUND(16) TF_ROUND(24)
  x0 += k1; x1 += k2 + 4u;
  TF_ROUND(13) TF_ROUND(15) TF_ROUND(26) TF_ROUND(6)
  x0 += k2; x1 += k0 + 5u;
}

// ---------------- front: mask + PRNG + fixed-threshold compaction ----------------
// keep iff top-5 bits of the 23-bit random == 0x1F (keep-prob 1/32). Keep-set is
// upward-closed in key order; E[survivors] ~2715 >= 2048 at ~13 sigma, so the
// exact top-2048 is a subset of the survivors. Unused slots are zeroed (bit43
// marker distinguishes real keys), so the back-end sweeps the array blindly.
__global__ __launch_bounds__(256) void k_front(
    const float* __restrict__ pfegc, const float* __restrict__ ppre,
    const float* __restrict__ gt,
    uint32_t kp0, uint32_t kp1, uint32_t kn0, uint32_t kn1,
    uint64_t* __restrict__ seg) {
  __shared__ uint32_t cnt2[2];
  int t = threadIdx.x;
  uint32_t b = blockIdx.x;
  if (t < 2) cnt2[t] = 0;
  if (t < 2 * (int)SEGCAP) {                // zero-fill this block's two segments
    uint32_t list = (uint32_t)t / SEGCAP, slot = (uint32_t)t % SEGCAP;
    seg[((size_t)list * NSEG + b) * SEGCAP + slot] = 0ull;
  }
  __syncthreads();
  uint32_t base = b * 1024u + (uint32_t)t * 4u;
  float4 pf = *(const float4*)(pfegc + base);
  float pfa[4] = { pf.x, pf.y, pf.z, pf.w };
  bool any = (pf.x >= 0.5f) || (pf.y >= 0.5f) || (pf.z >= 0.5f) || (pf.w >= 0.5f);
  if (any) {
    uint32_t hw = base & (HW - 1u);
    uint32_t bb = base >> 18;                 // base..base+3 share the image
    const float* pp = ppre + (size_t)bb * 3u * HW + hw;
    float4 p0 = *(const float4*)pp;
    float4 p1 = *(const float4*)(pp + HW);
    float4 p2 = *(const float4*)(pp + 2u * HW);
    float4 g4 = *(const float4*)(gt + base);
    float p0a[4] = { p0.x, p0.y, p0.z, p0.w };
    float p1a[4] = { p1.x, p1.y, p1.z, p1.w };
    float p2a[4] = { p2.x, p2.y, p2.z, p2.w };
    float ga[4]  = { g4.x, g4.y, g4.z, g4.w };
    #pragma unroll
    for (int j = 0; j < 4; ++j) {
      if (pfa[j] >= 0.5f && p0a[j] >= p1a[j] && p0a[j] >= p2a[j]) {
        uint32_t i = base + (uint32_t)j;
        bool gfg = ga[j] > 0.5f;
        uint32_t x0 = 0u, x1 = i;
        threefry2x32_(gfg ? kp0 : kn0, gfg ? kp1 : kn1, x0, x1);
        uint32_t r23 = (x0 ^ x1) >> 9;
        if ((r23 >> 18) == 0x1Fu) {           // fixed prefilter, keep-prob 1/32
          uint32_t list = gfg ? 0u : 1u;
          uint32_t r = atomicAdd(&cnt2[list], 1u);     // u32 LDS atomic, rare
          if (r < SEGCAP)
            seg[((size_t)list * NSEG + b) * SEGCAP + r] =
                (1ull << 43) | ((uint64_t)r23 << 20) | (uint64_t)(0xFFFFFu ^ i);
        }
      }
    }
  }
}

// ---------------- select exact top-2048 (1 block/list) ----------------
// count -> scan -> scatter sweep; 16B vector loads (global_load_dwordx4).
// Then 4-round 11-bit radix select; survivors -> idxbuf.
__global__ __launch_bounds__(256) void k_sel(
    const uint64_t* __restrict__ seg, uint32_t* __restrict__ idxbuf) {
  __shared__ uint64_t dense[DENSECAP];   // 28 KB
  __shared__ uint32_t hist[2048];        // 8 KB
  __shared__ uint32_t part[256];
  __shared__ uint32_t skk, rank, ntot;
  __shared__ int gsel;
  __shared__ uint64_t spref;
  int t = threadIdx.x;
  int list = blockIdx.x;
  uint32_t lane = (uint32_t)t & 63u;
  if (t == 0) { spref = 0ull; skk = NSEL; rank = 0; }
  const uint4* sp4 = (const uint4*)(seg + (size_t)list * NSEG * SEGCAP);
  // ---- Phase A: count valid keys (bit43 marker); 16B coalesced loads ----
  uint32_t c = 0;
  #pragma unroll
  for (int it = 0; it < 32; ++it) {
    uint4 v = sp4[(uint32_t)it * 256u + (uint32_t)t];
    c += ((v.y >> 11) & 1u) + ((v.w >> 11) & 1u);   // bit43 = bit11 of high word
  }
  part[t] = c;
  __syncthreads();
  for (int off = 1; off < 256; off <<= 1) {
    uint32_t x = part[t];
    uint32_t add = (t >= off) ? part[t - off] : 0u;
    __syncthreads();
    part[t] = x + add;
    __syncthreads();
  }
  uint32_t wbase = part[t] - c;          // exclusive prefix = this thread's base
  if (t == 255) ntot = part[255];
  // ---- Phase B: re-load (L2-hot) and scatter to dense ----
  #pragma unroll
  for (int it = 0; it < 32; ++it) {
    uint4 v = sp4[(uint32_t)it * 256u + (uint32_t)t];
    uint64_t k0 = ((uint64_t)v.y << 32) | v.x;
    uint64_t k1 = ((uint64_t)v.w << 32) | v.z;
    if (k0 >> 43) { if (wbase < DENSECAP) dense[wbase] = k0; ++wbase; }
    if (k1 >> 43) { if (wbase < DENSECAP) dense[wbase] = k1; ++wbase; }
  }
  __syncthreads();
  uint32_t n = ntot; if (n > DENSECAP) n = DENSECAP;
  // ---- 4-round 11-bit radix select of the exact 2048th-largest key ----
  for (int r = 0; r < 4; ++r) {
    #pragma unroll
    for (int e = 0; e < 8; ++e) hist[t * 8 + e] = 0;
    __syncthreads();
    int csp = 44 - 11 * r;
    int cs = csp - 11;
    uint64_t pref = spref;
    for (uint32_t j = t; j < n; j += 256) {
      uint64_t key = dense[j];
      if ((key >> csp) == pref)
        atomicAdd(&hist[(uint32_t)(key >> cs) & 0x7FFu], 1u);
    }
    __syncthreads();
    uint32_t ss = 0;
    #pragma unroll
    for (int e = 0; e < 8; ++e) ss += hist[t * 8 + e];
    part[t] = ss;
    __syncthreads();
    for (int off = 1; off < 256; off <<= 1) {
      uint32_t x = part[t];
      uint32_t y = (t + off < 256) ? part[t + off] : 0u;
      __syncthreads();
      part[t] = x + y;
      __syncthreads();
    }
    uint32_t k = skk;
    if (part[t] >= k && (t == 255 || part[t + 1] < k)) gsel = t;
    __syncthreads();
    if (t == 0) {
      int g = gsel;
      uint32_t cum = (g < 255) ? part[g + 1] : 0u;
      int d = g * 8;
      for (int e = g * 8 + 7; e >= g * 8; --e) {
        uint32_t he = hist[e];
        if (cum + he >= k) { d = e; break; }
        cum += he;
      }
      skk = k - cum;
      spref = (pref << 11) | (uint64_t)(uint32_t)d;
    }
    __syncthreads();
  }
  // ---- collect survivor indices (ballot-aggregated; exactly 2048, unique keys) ----
  uint64_t thr = spref;
  uint32_t niter = (n + 255u) >> 8;
  for (uint32_t it2 = 0; it2 < niter; ++it2) {
    uint32_t j = it2 * 256u + (uint32_t)t;
    uint64_t key = 0ull;
    bool v = false;
    if (j < n) { key = dense[j]; v = key >= thr; }
    unsigned long long m = __ballot(v);
    uint32_t bs = 0;
    if (lane == 0) bs = atomicAdd(&rank, (uint32_t)__popcll(m));
    bs = (uint32_t)__shfl((int)bs, 0, 64);
    if (v) {
      uint32_t s = bs + (uint32_t)__popcll(m & ((1ull << lane) - 1ull));
      if (s < NSEL)
        idxbuf[(uint32_t)list * NSEL + s] = 0xFFFFFu ^ (uint32_t)(key & 0xFFFFFu);
    }
  }
}

// ---------------- project: v = y/|proj|, w = G v (1 point/thread, 16 blocks) ----------------
__global__ __launch_bounds__(256) void k_proj(
    const uint32_t* __restrict__ idxbuf, const float* __restrict__ Wm,
    const float* __restrict__ bfc, const float* __restrict__ d1,
    float* __restrict__ va, float* __restrict__ wa) {
  __shared__ float sG[25];
  __shared__ float sGw[4][25];
  int t = threadIdx.x;
  // ---- G = [W|b]^T [W|b] via shuffle reduction (no atomics) ----
  {
    float4 wr = *(const float4*)(Wm + t * 4);
    float av[5] = { wr.x, wr.y, wr.z, wr.w, bfc[t] };
    int lane = t & 63, wvi = t >> 6;
    #pragma unroll
    for (int p = 0; p < 5; ++p)
      #pragma unroll
      for (int q = p; q < 5; ++q) {
        float g = av[p] * av[q];
        #pragma unroll
        for (int off = 32; off > 0; off >>= 1)
          g += __shfl_xor(g, off, 64);
        if (lane == 0) sGw[wvi][p * 5 + q] = g;
      }
  }
  __syncthreads();
  if (t < 25) {
    int p = t / 5, q = t % 5;
    int pp = p < q ? p : q, qq = p < q ? q : p;
    sG[t] = sGw[0][pp * 5 + qq] + sGw[1][pp * 5 + qq]
          + sGw[2][pp * 5 + qq] + sGw[3][pp * 5 + qq];
  }
  __syncthreads();
  uint32_t tg = blockIdx.x * 256u + (uint32_t)t;      // 0..4095
  uint32_t idx = idxbuf[tg] & (NPIX - 1u);
  uint32_t hw = idx & (HW - 1u);
  uint32_t bb = idx >> 18;
  const float* f = d1 + ((size_t)bb << 20) + hw;
  float y[5] = { f[0], f[HW], f[2u * HW], f[3u * HW], 1.0f };
  float z[5]; float n2 = 0.f;
  #pragma unroll
  for (int p = 0; p < 5; ++p) {
    float acc = 0.f;
    #pragma unroll
    for (int q = 0; q < 5; ++q) acc += sG[p * 5 + q] * y[q];
    z[p] = acc; n2 += acc * y[p];                     // = |proj|^2
  }
  n2 = fmaxf(n2, 0.f);
  float inv = 1.0f / fmaxf(sqrtf(n2), 1e-8f);
  uint32_t s5 = tg * 5u;
  #pragma unroll
  for (int p = 0; p < 5; ++p) {
    va[s5 + p] = y[p] * inv;
    wa[s5 + p] = z[p] * inv;
  }
}

// ---------------- pairwise loss: per-block partials, plain stores ----------------
__global__ __launch_bounds__(256) void k_pair(
    const float* __restrict__ va, const float* __restrict__ wa,
    float* __restrict__ psum, uint32_t* __restrict__ pnnz) {
  __shared__ float sv[128 * 5], sw[128 * 5];
  __shared__ float rs[256];
  __shared__ uint32_t rn[256];
  int i0 = blockIdx.x * 128, j0 = blockIdx.y * 128;
  int t = threadIdx.x;
  for (int u = t; u < 640; u += 256) { sv[u] = va[i0 * 5 + u]; sw[u] = wa[j0 * 5 + u]; }
  __syncthreads();
  int ty = t >> 4, tx = t & 15;
  float rv[8][5], rw[8][5];
  #pragma unroll
  for (int a = 0; a < 8; ++a)
    #pragma unroll
    for (int p = 0; p < 5; ++p) {
      rv[a][p] = sv[(ty * 8 + a) * 5 + p];
      rw[a][p] = sw[(tx * 8 + a) * 5 + p];
    }
  float lsum = 0.f; uint32_t lnz = 0;
  #pragma unroll
  for (int a = 0; a < 8; ++a) {
    int gi = i0 + ty * 8 + a;
    #pragma unroll
    for (int q = 0; q < 8; ++q) {
      int gj = j0 + tx * 8 + q;
      float c = rv[a][0]*rw[q][0] + rv[a][1]*rw[q][1] + rv[a][2]*rw[q][2]
              + rv[a][3]*rw[q][3] + rv[a][4]*rw[q][4];
      float s = c * 10.0f;                     // / TAU
      if (gi != gj) {
        if (((gi ^ gj) & 2048) == 0) {         // same block (pos-pos / neg-neg)
          float m = fmaxf(0.5f - s, 0.f);
          lsum += m * m;
          lnz += (m > 0.f) ? 1u : 0u;
        } else {                               // cross block
          lsum += s * s;
          lnz += (s != 0.f) ? 1u : 0u;
        }
      }
    }
  }
  rs[t] = lsum; rn[t] = lnz;
  __syncthreads();
  for (int off = 128; off > 0; off >>= 1) {
    if (t < off) { rs[t] += rs[t + off]; rn[t] += rn[t + off]; }
    __syncthreads();
  }
  if (t == 0) {
    int bid = blockIdx.y * gridDim.x + blockIdx.x;
    psum[bid] = rs[0];
    pnnz[bid] = rn[0];
  }
}

__global__ __launch_bounds__(256) void k_final(const float* __restrict__ psum,
                                               const uint32_t* __restrict__ pnnz,
                                               float* __restrict__ out) {
  __shared__ float rs[256];
  __shared__ uint32_t rn[256];
  int t = threadIdx.x;
  float s = 0.f; uint32_t nz = 0;
  for (int j = t; j < 1024; j += 256) { s += psum[j]; nz += pnnz[j]; }
  rs[t] = s; rn[t] = nz;
  __syncthreads();
  for (int off = 128; off > 0; off >>= 1) {
    if (t < off) { rs[t] += rs[t + off]; rn[t] += rn[t + off]; }
    __syncthreads();
  }
  if (t == 0) out[0] = rs[0] / (float)rn[0];
}

extern "C" void kernel_launch(void* const* d_in, const int* in_sizes, int n_in,
                              void* d_out, int out_size, void* d_ws, size_t ws_size,
                              hipStream_t stream) {
  (void)in_sizes; (void)n_in; (void)out_size; (void)ws_size;
  const float* d1    = (const float*)d_in[0];
  const float* pfegc = (const float*)d_in[1];
  const float* ppre  = (const float*)d_in[2];
  const float* gt    = (const float*)d_in[3];
  const float* W     = (const float*)d_in[4];
  const float* bfc   = (const float*)d_in[5];
  float* out = (float*)d_out;

  uint8_t* base = (uint8_t*)d_ws;
  uint64_t* seg    = (uint64_t*)(base + OFF_SEG);
  uint32_t* idxbuf = (uint32_t*)(base + OFF_IDX);
  float*    va     = (float*)(base + OFF_VA);
  float*    wa     = (float*)(base + OFF_WA);
  float*    psum   = (float*)(base + OFF_PSUM);
  uint32_t* pnnz   = (uint32_t*)(base + OFF_PNNZ);

  // jax.random.key(42), partitionable split: kp = tf(0,42,{0,0}), kn = tf(0,42,{0,1})
  uint32_t kp0 = 0u, kp1 = 0u; threefry2x32_(0u, 42u, kp0, kp1);
  uint32_t kn0 = 0u, kn1 = 1u; threefry2x32_(0u, 42u, kn0, kn1);

  k_front<<<NSEG, 256, 0, stream>>>(pfegc, ppre, gt, kp0, kp1, kn0, kn1, seg);
  k_sel<<<2, 256, 0, stream>>>(seg, idxbuf);
  k_proj<<<16, 256, 0, stream>>>(idxbuf, W, bfc, d1, va, wa);
  k_pair<<<dim3(32, 32), 256, 0, stream>>>(va, wa, psum, pnnz);
  k_final<<<1, 256, 0, stream>>>(psum, pnnz, out);
}